// Round 1
// baseline (9876.734 us; speedup 1.0000x reference)
//
#include <hip/hip_runtime.h>

typedef unsigned short u16;
typedef __attribute__((ext_vector_type(8))) short short8;
typedef __attribute__((ext_vector_type(4))) float f4;
typedef __attribute__((ext_vector_type(4))) unsigned short us4;

#define MFMA_BF16(a, b, c) __builtin_amdgcn_mfma_f32_16x16x32_bf16((a), (b), (c), 0, 0, 0)

#define Bsz 64
#define Ssz 1024
#define Isz 512
#define Hsz 512
#define G4  2048      // 4*H packed gate rows
#define SCH 128       // timesteps per chunk
#define NCHUNK 8
#define SCAN_NB 64    // scan grid (<= 256 CUs -> co-resident)

// ---- workspace layout (bytes). total ~75.5 MB ----
#define WS_CNT   0           // 1024 * 4        step counters
#define WS_BIAS  4096        // 2048 * 4        combined bias, packed order
#define WS_HBUF  16384       // 2 * 32768 * 2   h double buffer, bf16 [b][k]
#define WS_CBUF  147456      // 32768 * 4       c state fp32 [b][j]
#define WS_WI    524288      // 2048*512*2      Wi bf16 packed [row'][k]
#define WS_WH    2621440     // 2048*512*2      Wh bf16 packed [row'][k]
#define WS_XC    8388608     // 64*128*2048*4   x_proj chunk fp32 [b][s_local][row']

#define HF_OFF ((size_t)Bsz * Ssz * Hsz)           // 33554432
#define CF_OFF (HF_OFF + (size_t)Bsz * Hsz)

__device__ __forceinline__ u16 bf16rne(float f) {
    unsigned int x = __float_as_uint(f);
    unsigned int r = (x + 0x7fffu + ((x >> 16) & 1u)) >> 16;
    return (u16)r;
}
__device__ __forceinline__ float sigf(float x) { return 1.0f / (1.0f + __expf(-x)); }
__device__ __forceinline__ float tanh_(float x) { return 1.0f - 2.0f / (__expf(2.0f * x) + 1.0f); }

// ------------------------------------------------------------------
// prep: pack weights (bf16, gate-interleaved rows), combine biases,
// init h (bf16, buffer 1) and c state, zero step counters.
// ------------------------------------------------------------------
struct PrepArgs {
    const float* h0; const float* c0;
    const float* wi[4]; const float* wh[4];
    const float* bi[4]; const float* bh[4];   // bh order fixed to (i,f,g,o) by host
    u16* Wi; u16* Wh; float* bias; u16* hbuf; float* cbuf; int* cnt;
};
#define PREP_TOT (1048576 + 1048576 + 2048 + 32768 + 32768 + 1024)

__global__ void lstm_prep(PrepArgs a) {
    long i = (long)blockIdx.x * 256 + threadIdx.x;
    if (i < 1048576) {                       // Wi pack
        int rowp = (int)(i >> 9), k = (int)(i & 511);
        int unit = rowp >> 2, gate = rowp & 3;
        a.Wi[i] = bf16rne(a.wi[gate][unit * Isz + k]);
    } else if (i < 2097152) {                // Wh pack
        long j = i - 1048576;
        int rowp = (int)(j >> 9), k = (int)(j & 511);
        int unit = rowp >> 2, gate = rowp & 3;
        a.Wh[j] = bf16rne(a.wh[gate][unit * Hsz + k]);
    } else if (i < 2097152 + 2048) {         // bias combine (packed order)
        int j = (int)(i - 2097152);
        int unit = j >> 2, gate = j & 3;
        a.bias[j] = a.bi[gate][unit] + a.bh[gate][unit];
    } else if (i < 2097152 + 2048 + 32768) { // h0 -> bf16 buffer 1
        int j = (int)(i - (2097152 + 2048));
        a.hbuf[32768 + j] = bf16rne(a.h0[j]);
    } else if (i < 2097152 + 2048 + 65536) { // c0 -> c state
        int j = (int)(i - (2097152 + 2048 + 32768));
        a.cbuf[j] = a.c0[j];
    } else if (i < PREP_TOT) {               // zero counters
        a.cnt[i - (2097152 + 2048 + 65536)] = 0;
    }
}

// ------------------------------------------------------------------
// x_proj GEMM: one chunk of 128 timesteps.
// A = inputs[b][t0+s][k] fp32 (converted to bf16 in staging), B = Wi packed bf16.
// Block = 128(s) x 128(n) tile; grid 64*16; 4 waves each 64x64.
// ------------------------------------------------------------------
__global__ __launch_bounds__(256) void xproj_gemm(
    const float* __restrict__ inp, const u16* __restrict__ Wi,
    float* __restrict__ xc, int t0)
{
    __shared__ u16 Al[128 * 40];   // [m][k] pad 32->40 (2-way max, free)
    __shared__ u16 Bl[128 * 40];   // [n][k]
    const int tid = threadIdx.x;
    const int L = tid & 63, w = tid >> 6;
    const int q = L >> 4, lm = L & 15;
    const int nt = blockIdx.x & 15, b = blockIdx.x >> 4;
    const float* Abase = inp + ((size_t)b * Ssz + t0) * Isz;
    const u16* Bbase = Wi + (size_t)nt * 128 * Isz;
    const int mh = (w & 1) * 64, nh = (w >> 1) * 64;

    f4 acc[4][4];
#pragma unroll
    for (int i = 0; i < 4; ++i)
#pragma unroll
        for (int j = 0; j < 4; ++j) acc[i][j] = (f4){0.f, 0.f, 0.f, 0.f};

    for (int kt = 0; kt < 16; ++kt) {
        const int k0 = kt * 32;
        // stage A (fp32 -> bf16): 1024 float4 items
#pragma unroll
        for (int r = 0; r < 4; ++r) {
            int flat = tid + r * 256;
            int m = flat >> 3, kq = flat & 7;
            f4 v = *(const f4*)(Abase + (size_t)m * Isz + k0 + kq * 4);
            us4 h = {bf16rne(v.x), bf16rne(v.y), bf16rne(v.z), bf16rne(v.w)};
            *(us4*)(&Al[m * 40 + kq * 4]) = h;
        }
        // stage B: 512 16B items
#pragma unroll
        for (int r = 0; r < 2; ++r) {
            int flat = tid + r * 256;
            int n = flat >> 2, kq = flat & 3;
            *(short8*)(&Bl[n * 40 + kq * 8]) =
                *(const short8*)(Bbase + (size_t)n * Isz + k0 + kq * 8);
        }
        __syncthreads();
        short8 af[4], bfr[4];
#pragma unroll
        for (int i = 0; i < 4; ++i)
            af[i] = *(const short8*)(&Al[(mh + i * 16 + lm) * 40 + q * 8]);
#pragma unroll
        for (int j = 0; j < 4; ++j)
            bfr[j] = *(const short8*)(&Bl[(nh + j * 16 + lm) * 40 + q * 8]);
#pragma unroll
        for (int i = 0; i < 4; ++i)
#pragma unroll
            for (int j = 0; j < 4; ++j)
                acc[i][j] = MFMA_BF16(af[i], bfr[j], acc[i][j]);
        __syncthreads();
    }
    // epilogue: xc[b][s_local][n_global]
    float* Obase = xc + (size_t)b * SCH * G4 + (size_t)nt * 128;
#pragma unroll
    for (int i = 0; i < 4; ++i)
#pragma unroll
        for (int j = 0; j < 4; ++j)
#pragma unroll
            for (int r = 0; r < 4; ++r) {
                int m = mh + i * 16 + q * 4 + r;   // s_local
                int n = nh + j * 16 + lm;
                Obase[(size_t)m * G4 + n] = acc[i][j][r];
            }
}

// ------------------------------------------------------------------
// persistent scan: 64 blocks, each owns 8 hidden units (32 packed rows).
// Wh fragments register-resident; h broadcast via global bf16 double buffer;
// per-step device-scope release/acquire + per-step counter barrier.
// ------------------------------------------------------------------
__global__ __launch_bounds__(256, 1) void lstm_scan(
    const float* __restrict__ xc, const u16* __restrict__ Whp,
    const float* __restrict__ bias, u16* __restrict__ hbuf,
    float* __restrict__ cbuf, int* __restrict__ cnt,
    float* __restrict__ out, int t0)
{
    __shared__ float gate_buf[64 * 32];   // [b][n_local]
    const int tid = threadIdx.x, bid = blockIdx.x;
    const int L = tid & 63, w = tid >> 6;
    const int q = L >> 4, lm = L & 15;
    const int row0 = bid * 32;   // packed gate rows owned
    const int j0 = bid * 8;      // hidden units owned
    const int myb = w * 16 + lm; // batch row for A fragment

    // loop-invariant B fragments (weights) in registers: 32 x 16B = 128 VGPRs
    short8 wb[16][2];
#pragma unroll
    for (int kt = 0; kt < 16; ++kt)
#pragma unroll
        for (int jt = 0; jt < 2; ++jt) {
            int n = row0 + jt * 16 + lm;
            wb[kt][jt] = *(const short8*)(Whp + (size_t)n * Hsz + kt * 32 + q * 8);
        }

    // epilogue mapping: thread -> (batch be, units u0,u0+1)
    const int be = tid >> 2;
    const int u0 = (tid & 3) * 2;
    const f4 bias0 = *(const f4*)(bias + row0 + u0 * 4);
    const f4 bias1 = *(const f4*)(bias + row0 + u0 * 4 + 4);
    float c0r = cbuf[be * Hsz + j0 + u0];
    float c1r = cbuf[be * Hsz + j0 + u0 + 1];

    for (int t = t0; t < t0 + SCH; ++t) {
        const int sl = t - t0;
        // x prefetch (independent of h -> issue before the barrier)
        const float* xrow = xc + ((size_t)be * SCH + sl) * G4 + row0 + u0 * 4;
        f4 xv0 = *(const f4*)(xrow);
        f4 xv1 = *(const f4*)(xrow + 4);

        if (t > t0) {
            if (tid == 0) {
                while (__hip_atomic_load(&cnt[t - 1], __ATOMIC_RELAXED,
                                         __HIP_MEMORY_SCOPE_AGENT) < SCAN_NB)
                    __builtin_amdgcn_s_sleep(1);
            }
            __syncthreads();
            __builtin_amdgcn_fence(__ATOMIC_ACQUIRE, "agent");
        }

        const u16* hp = hbuf + (size_t)((t & 1) ^ 1) * 32768;  // h(t-1)
        short8 af[16];
#pragma unroll
        for (int kt = 0; kt < 16; ++kt)
            af[kt] = *(const short8*)(hp + (size_t)myb * Hsz + kt * 32 + q * 8);

        f4 acc0 = (f4){0.f, 0.f, 0.f, 0.f}, acc1 = acc0;
#pragma unroll
        for (int kt = 0; kt < 16; ++kt) {
            acc0 = MFMA_BF16(af[kt], wb[kt][0], acc0);
            acc1 = MFMA_BF16(af[kt], wb[kt][1], acc1);
        }

        __syncthreads();   // previous epilogue reads of gate_buf are done
#pragma unroll
        for (int r = 0; r < 4; ++r) {
            int brow = w * 16 + q * 4 + r;
            gate_buf[brow * 32 + lm] = acc0[r];
            gate_buf[brow * 32 + 16 + lm] = acc1[r];
        }
        __syncthreads();

        f4 g0 = *(const f4*)(&gate_buf[be * 32 + u0 * 4]);
        f4 g1 = *(const f4*)(&gate_buf[be * 32 + u0 * 4 + 4]);
        g0 += xv0 + bias0;
        g1 += xv1 + bias1;
        float i1 = sigf(g0.x), f1 = sigf(g0.y), gg1 = tanh_(g0.z), o1 = sigf(g0.w);
        c0r = f1 * c0r + i1 * gg1;
        float h1 = o1 * tanh_(c0r);
        float i2 = sigf(g1.x), f2 = sigf(g1.y), gg2 = tanh_(g1.z), o2 = sigf(g1.w);
        c1r = f2 * c1r + i2 * gg2;
        float h2 = o2 * tanh_(c1r);

        u16* hw = hbuf + (size_t)(t & 1) * 32768 + be * Hsz + j0 + u0;
        hw[0] = bf16rne(h1);
        hw[1] = bf16rne(h2);
        float* op = out + ((size_t)be * Ssz + t) * Hsz + j0 + u0;
        op[0] = h1;
        op[1] = h2;
        if (t == Ssz - 1) {
            out[HF_OFF + be * Hsz + j0 + u0] = h1;
            out[HF_OFF + be * Hsz + j0 + u0 + 1] = h2;
            out[CF_OFF + be * Hsz + j0 + u0] = c0r;
            out[CF_OFF + be * Hsz + j0 + u0 + 1] = c1r;
        }

        __syncthreads();   // drains vmcnt: all h stores complete to L2
        if (tid == 0) {
            __builtin_amdgcn_fence(__ATOMIC_RELEASE, "agent");  // wbl2 -> visible device-wide
            __hip_atomic_fetch_add(&cnt[t], 1, __ATOMIC_RELAXED, __HIP_MEMORY_SCOPE_AGENT);
        }
    }
    // persist c for next chunk
    cbuf[be * Hsz + j0 + u0] = c0r;
    cbuf[be * Hsz + j0 + u0 + 1] = c1r;
}

// ------------------------------------------------------------------
extern "C" void kernel_launch(void* const* d_in, const int* in_sizes, int n_in,
                              void* d_out, int out_size, void* d_ws, size_t ws_size,
                              hipStream_t stream) {
    const float* inputs = (const float*)d_in[0];
    char* W = (char*)d_ws;
    int*  cnt  = (int*)(W + WS_CNT);
    float* bias = (float*)(W + WS_BIAS);
    u16*  hbuf = (u16*)(W + WS_HBUF);
    float* cbuf = (float*)(W + WS_CBUF);
    u16*  Wi   = (u16*)(W + WS_WI);
    u16*  Wh   = (u16*)(W + WS_WH);
    float* xch  = (float*)(W + WS_XC);

    PrepArgs a;
    a.h0 = (const float*)d_in[1];
    a.c0 = (const float*)d_in[2];
    for (int g = 0; g < 4; ++g) {
        a.wi[g] = (const float*)d_in[3 + g];
        a.wh[g] = (const float*)d_in[7 + g];
        a.bi[g] = (const float*)d_in[11 + g];
    }
    // dict order at the tail is b_hi, b_hf, b_ho, b_hg -> remap to (i,f,g,o)
    a.bh[0] = (const float*)d_in[15];
    a.bh[1] = (const float*)d_in[16];
    a.bh[2] = (const float*)d_in[18];
    a.bh[3] = (const float*)d_in[17];
    a.Wi = Wi; a.Wh = Wh; a.bias = bias; a.hbuf = hbuf; a.cbuf = cbuf; a.cnt = cnt;

    lstm_prep<<<(PREP_TOT + 255) / 256, 256, 0, stream>>>(a);

    float* out = (float*)d_out;
    for (int c = 0; c < NCHUNK; ++c) {
        int t0 = c * SCH;
        xproj_gemm<<<dim3(64 * 16), 256, 0, stream>>>(inputs, Wi, xch, t0);
        lstm_scan<<<dim3(SCAN_NB), 256, 0, stream>>>(xch, Wh, bias, hbuf, cbuf, cnt, out, t0);
    }
}

// Round 2
// 7152.541 us; speedup vs baseline: 1.3809x; 1.3809x over previous
//
#include <hip/hip_runtime.h>

typedef unsigned short u16;
typedef unsigned long long u64;
typedef __attribute__((ext_vector_type(8))) short short8;
typedef __attribute__((ext_vector_type(4))) float f4;
typedef __attribute__((ext_vector_type(4))) unsigned short us4;

#define MFMA_BF16(a, b, c) __builtin_amdgcn_mfma_f32_16x16x32_bf16((a), (b), (c), 0, 0, 0)

#define Bsz 64
#define Ssz 1024
#define Isz 512
#define Hsz 512
#define G4  2048      // 4*H packed gate rows
#define SCH 128       // timesteps per chunk
#define NCHUNK 8
#define SCAN_NB 64    // scan grid (<= 256 CUs -> co-resident)

// ---- workspace layout (bytes). total ~75.5 MB ----
#define WS_CNT   0           // 1024 * 4        step counters
#define WS_BIAS  4096        // 2048 * 4        combined bias, packed order
#define WS_HBUF  16384       // 2 * 32768 * 2   h double buffer, bf16 [b][k]
#define WS_CBUF  147456      // 32768 * 4       c state fp32 [b][j]
#define WS_WI    524288      // 2048*512*2      Wi bf16 packed [row'][k]
#define WS_WH    2621440     // 2048*512*2      Wh bf16 packed [row'][k]
#define WS_XC    8388608     // 64*128*2048*4   x_proj chunk fp32 [b][s_local][row']

#define HF_OFF ((size_t)Bsz * Ssz * Hsz)           // 33554432
#define CF_OFF (HF_OFF + (size_t)Bsz * Hsz)

__device__ __forceinline__ u16 bf16rne(float f) {
    unsigned int x = __float_as_uint(f);
    unsigned int r = (x + 0x7fffu + ((x >> 16) & 1u)) >> 16;
    return (u16)r;
}
__device__ __forceinline__ float sigf(float x) { return 1.0f / (1.0f + __expf(-x)); }
__device__ __forceinline__ float tanh_(float x) { return 1.0f - 2.0f / (__expf(2.0f * x) + 1.0f); }

// ------------------------------------------------------------------
// prep: pack weights (bf16, gate-interleaved rows), combine biases,
// init h (bf16, buffer 1) and c state, zero step counters.
// ------------------------------------------------------------------
struct PrepArgs {
    const float* h0; const float* c0;
    const float* wi[4]; const float* wh[4];
    const float* bi[4]; const float* bh[4];   // bh order fixed to (i,f,g,o) by host
    u16* Wi; u16* Wh; float* bias; u16* hbuf; float* cbuf; int* cnt;
};
#define PREP_TOT (1048576 + 1048576 + 2048 + 32768 + 32768 + 1024)

__global__ void lstm_prep(PrepArgs a) {
    long i = (long)blockIdx.x * 256 + threadIdx.x;
    if (i < 1048576) {                       // Wi pack
        int rowp = (int)(i >> 9), k = (int)(i & 511);
        int unit = rowp >> 2, gate = rowp & 3;
        a.Wi[i] = bf16rne(a.wi[gate][unit * Isz + k]);
    } else if (i < 2097152) {                // Wh pack
        long j = i - 1048576;
        int rowp = (int)(j >> 9), k = (int)(j & 511);
        int unit = rowp >> 2, gate = rowp & 3;
        a.Wh[j] = bf16rne(a.wh[gate][unit * Hsz + k]);
    } else if (i < 2097152 + 2048) {         // bias combine (packed order)
        int j = (int)(i - 2097152);
        int unit = j >> 2, gate = j & 3;
        a.bias[j] = a.bi[gate][unit] + a.bh[gate][unit];
    } else if (i < 2097152 + 2048 + 32768) { // h0 -> bf16 buffer 1 (device-coherent store)
        int j = (int)(i - (2097152 + 2048));
        __hip_atomic_store(&a.hbuf[32768 + j], bf16rne(a.h0[j]),
                           __ATOMIC_RELAXED, __HIP_MEMORY_SCOPE_AGENT);
    } else if (i < 2097152 + 2048 + 65536) { // c0 -> c state
        int j = (int)(i - (2097152 + 2048 + 32768));
        a.cbuf[j] = a.c0[j];
    } else if (i < PREP_TOT) {               // zero counters
        __hip_atomic_store(&a.cnt[i - (2097152 + 2048 + 65536)], 0,
                           __ATOMIC_RELAXED, __HIP_MEMORY_SCOPE_AGENT);
    }
}

// ------------------------------------------------------------------
// x_proj GEMM: one chunk of 128 timesteps.
// ------------------------------------------------------------------
__global__ __launch_bounds__(256) void xproj_gemm(
    const float* __restrict__ inp, const u16* __restrict__ Wi,
    float* __restrict__ xc, int t0)
{
    __shared__ u16 Al[128 * 40];   // [m][k] pad 32->40
    __shared__ u16 Bl[128 * 40];   // [n][k]
    const int tid = threadIdx.x;
    const int L = tid & 63, w = tid >> 6;
    const int q = L >> 4, lm = L & 15;
    const int nt = blockIdx.x & 15, b = blockIdx.x >> 4;
    const float* Abase = inp + ((size_t)b * Ssz + t0) * Isz;
    const u16* Bbase = Wi + (size_t)nt * 128 * Isz;
    const int mh = (w & 1) * 64, nh = (w >> 1) * 64;

    f4 acc[4][4];
#pragma unroll
    for (int i = 0; i < 4; ++i)
#pragma unroll
        for (int j = 0; j < 4; ++j) acc[i][j] = (f4){0.f, 0.f, 0.f, 0.f};

    for (int kt = 0; kt < 16; ++kt) {
        const int k0 = kt * 32;
#pragma unroll
        for (int r = 0; r < 4; ++r) {
            int flat = tid + r * 256;
            int m = flat >> 3, kq = flat & 7;
            f4 v = *(const f4*)(Abase + (size_t)m * Isz + k0 + kq * 4);
            us4 h = {bf16rne(v.x), bf16rne(v.y), bf16rne(v.z), bf16rne(v.w)};
            *(us4*)(&Al[m * 40 + kq * 4]) = h;
        }
#pragma unroll
        for (int r = 0; r < 2; ++r) {
            int flat = tid + r * 256;
            int n = flat >> 2, kq = flat & 3;
            *(short8*)(&Bl[n * 40 + kq * 8]) =
                *(const short8*)(Bbase + (size_t)n * Isz + k0 + kq * 8);
        }
        __syncthreads();
        short8 af[4], bfr[4];
#pragma unroll
        for (int i = 0; i < 4; ++i)
            af[i] = *(const short8*)(&Al[(mh + i * 16 + lm) * 40 + q * 8]);
#pragma unroll
        for (int j = 0; j < 4; ++j)
            bfr[j] = *(const short8*)(&Bl[(nh + j * 16 + lm) * 40 + q * 8]);
#pragma unroll
        for (int i = 0; i < 4; ++i)
#pragma unroll
            for (int j = 0; j < 4; ++j)
                acc[i][j] = MFMA_BF16(af[i], bfr[j], acc[i][j]);
        __syncthreads();
    }
    float* Obase = xc + (size_t)b * SCH * G4 + (size_t)nt * 128;
#pragma unroll
    for (int i = 0; i < 4; ++i)
#pragma unroll
        for (int j = 0; j < 4; ++j)
#pragma unroll
            for (int r = 0; r < 4; ++r) {
                int m = mh + i * 16 + q * 4 + r;   // s_local
                int n = nh + j * 16 + lm;
                Obase[(size_t)m * G4 + n] = acc[i][j][r];
            }
}

// ------------------------------------------------------------------
// persistent scan: fence-free device-coherent protocol.
// All cross-block data (hbuf, cnt) uses agent-scope relaxed atomics
// (sc1: stores write through L2, loads bypass stale L2 -> served by MALL,
// which is shared across XCDs). No buffer_wbl2 / buffer_inv anywhere.
// Ordering: __syncthreads drains vmcnt(0) before tid0 increments cnt[t];
// readers poll cnt (sc1) then load h (sc1) -> in-order issue guarantees
// the gather sees data that reached MALL before the increment.
// ------------------------------------------------------------------
__global__ __launch_bounds__(256, 1) void lstm_scan(
    const float* __restrict__ xc, const u16* __restrict__ Whp,
    const float* __restrict__ bias, u16* __restrict__ hbuf,
    float* __restrict__ cbuf, int* __restrict__ cnt,
    float* __restrict__ out, int t0)
{
    __shared__ float gate_buf[64 * 32];   // [b][n_local]
    const int tid = threadIdx.x, bid = blockIdx.x;
    const int L = tid & 63, w = tid >> 6;
    const int q = L >> 4, lm = L & 15;
    const int row0 = bid * 32;   // packed gate rows owned
    const int j0 = bid * 8;      // hidden units owned
    const int myb = w * 16 + lm; // batch row for A fragment

    // loop-invariant B fragments (weights) in registers: 32 x 16B = 128 VGPRs
    short8 wb[16][2];
#pragma unroll
    for (int kt = 0; kt < 16; ++kt)
#pragma unroll
        for (int jt = 0; jt < 2; ++jt) {
            int n = row0 + jt * 16 + lm;
            wb[kt][jt] = *(const short8*)(Whp + (size_t)n * Hsz + kt * 32 + q * 8);
        }

    const int be = tid >> 2;
    const int u0 = (tid & 3) * 2;
    const f4 bias0 = *(const f4*)(bias + row0 + u0 * 4);
    const f4 bias1 = *(const f4*)(bias + row0 + u0 * 4 + 4);
    float c0r = cbuf[be * Hsz + j0 + u0];
    float c1r = cbuf[be * Hsz + j0 + u0 + 1];

    for (int t = t0; t < t0 + SCH; ++t) {
        const int sl = t - t0;
        // x prefetch (independent of h -> in flight across the wait)
        const float* xrow = xc + ((size_t)be * SCH + sl) * G4 + row0 + u0 * 4;
        f4 xv0 = *(const f4*)(xrow);
        f4 xv1 = *(const f4*)(xrow + 4);

        if (t > t0) {
            if (tid == 0) {
                while (__hip_atomic_load(&cnt[t - 1], __ATOMIC_RELAXED,
                                         __HIP_MEMORY_SCOPE_AGENT) < SCAN_NB)
                    __builtin_amdgcn_s_sleep(1);
            }
            __syncthreads();
            __asm__ volatile("" ::: "memory");
        }

        // h(t-1) gather, device-coherent 8B loads
        const u64* hq = (const u64*)(hbuf + (size_t)((t & 1) ^ 1) * 32768)
                        + (size_t)myb * 128;
        union { short8 v; u64 q2[2]; } au[16];
#pragma unroll
        for (int kt = 0; kt < 16; ++kt) {
            au[kt].q2[0] = __hip_atomic_load(hq + kt * 8 + q * 2,
                                             __ATOMIC_RELAXED, __HIP_MEMORY_SCOPE_AGENT);
            au[kt].q2[1] = __hip_atomic_load(hq + kt * 8 + q * 2 + 1,
                                             __ATOMIC_RELAXED, __HIP_MEMORY_SCOPE_AGENT);
        }

        f4 acc0 = (f4){0.f, 0.f, 0.f, 0.f}, acc1 = acc0;
#pragma unroll
        for (int kt = 0; kt < 16; ++kt) {
            acc0 = MFMA_BF16(au[kt].v, wb[kt][0], acc0);
            acc1 = MFMA_BF16(au[kt].v, wb[kt][1], acc1);
        }

#pragma unroll
        for (int r = 0; r < 4; ++r) {
            int brow = w * 16 + q * 4 + r;
            gate_buf[brow * 32 + lm] = acc0[r];
            gate_buf[brow * 32 + 16 + lm] = acc1[r];
        }
        __syncthreads();

        f4 g0 = *(const f4*)(&gate_buf[be * 32 + u0 * 4]);
        f4 g1 = *(const f4*)(&gate_buf[be * 32 + u0 * 4 + 4]);
        g0 += xv0 + bias0;
        g1 += xv1 + bias1;
        float i1 = sigf(g0.x), f1 = sigf(g0.y), gg1 = tanh_(g0.z), o1 = sigf(g0.w);
        c0r = f1 * c0r + i1 * gg1;
        float h1 = o1 * tanh_(c0r);
        float i2 = sigf(g1.x), f2 = sigf(g1.y), gg2 = tanh_(g1.z), o2 = sigf(g1.w);
        c1r = f2 * c1r + i2 * gg2;
        float h2 = o2 * tanh_(c1r);

        // h(t) publish: packed u32 device-coherent store (write-through)
        unsigned int hv = (unsigned int)bf16rne(h1) | ((unsigned int)bf16rne(h2) << 16);
        unsigned int* hw = (unsigned int*)(hbuf + (size_t)(t & 1) * 32768
                                           + be * Hsz + j0 + u0);
        __hip_atomic_store(hw, hv, __ATOMIC_RELAXED, __HIP_MEMORY_SCOPE_AGENT);

        float* op = out + ((size_t)be * Ssz + t) * Hsz + j0 + u0;
        op[0] = h1;
        op[1] = h2;
        if (t == Ssz - 1) {
            out[HF_OFF + be * Hsz + j0 + u0] = h1;
            out[HF_OFF + be * Hsz + j0 + u0 + 1] = h2;
            out[CF_OFF + be * Hsz + j0 + u0] = c0r;
            out[CF_OFF + be * Hsz + j0 + u0 + 1] = c1r;
        }

        __syncthreads();   // emits s_waitcnt vmcnt(0) before s_barrier: h stores are at MALL
        if (tid == 0) {
            __asm__ volatile("" ::: "memory");
            __hip_atomic_fetch_add(&cnt[t], 1, __ATOMIC_RELAXED, __HIP_MEMORY_SCOPE_AGENT);
        }
    }
    cbuf[be * Hsz + j0 + u0] = c0r;
    cbuf[be * Hsz + j0 + u0 + 1] = c1r;
}

// ------------------------------------------------------------------
extern "C" void kernel_launch(void* const* d_in, const int* in_sizes, int n_in,
                              void* d_out, int out_size, void* d_ws, size_t ws_size,
                              hipStream_t stream) {
    const float* inputs = (const float*)d_in[0];
    char* W = (char*)d_ws;
    int*  cnt  = (int*)(W + WS_CNT);
    float* bias = (float*)(W + WS_BIAS);
    u16*  hbuf = (u16*)(W + WS_HBUF);
    float* cbuf = (float*)(W + WS_CBUF);
    u16*  Wi   = (u16*)(W + WS_WI);
    u16*  Wh   = (u16*)(W + WS_WH);
    float* xch  = (float*)(W + WS_XC);

    PrepArgs a;
    a.h0 = (const float*)d_in[1];
    a.c0 = (const float*)d_in[2];
    for (int g = 0; g < 4; ++g) {
        a.wi[g] = (const float*)d_in[3 + g];
        a.wh[g] = (const float*)d_in[7 + g];
        a.bi[g] = (const float*)d_in[11 + g];
    }
    // dict order at the tail is b_hi, b_hf, b_ho, b_hg -> remap to (i,f,g,o)
    a.bh[0] = (const float*)d_in[15];
    a.bh[1] = (const float*)d_in[16];
    a.bh[2] = (const float*)d_in[18];
    a.bh[3] = (const float*)d_in[17];
    a.Wi = Wi; a.Wh = Wh; a.bias = bias; a.hbuf = hbuf; a.cbuf = cbuf; a.cnt = cnt;

    lstm_prep<<<(PREP_TOT + 255) / 256, 256, 0, stream>>>(a);

    float* out = (float*)d_out;
    for (int c = 0; c < NCHUNK; ++c) {
        int t0 = c * SCH;
        xproj_gemm<<<dim3(64 * 16), 256, 0, stream>>>(inputs, Wi, xch, t0);
        lstm_scan<<<dim3(SCAN_NB), 256, 0, stream>>>(xch, Wh, bias, hbuf, cbuf, cnt, out, t0);
    }
}